// Round 4
// baseline (2109.288 us; speedup 1.0000x reference)
//
#include <hip/hip_runtime.h>
#include <hip/hip_bf16.h>
#include <stdint.h>

// CrossExpertRefinement on MI355X — round 4: pre-split bf16 hi/lo operands,
// register-staged LDS (r2-proven layout/swizzle), bf16x3 (3 MFMAs/product),
// fixed workspace footprint (no ws_size branching), fused epilogues.
//
// qkv_row = r*(S_row . Wg) - r*m*u + c   with Wg = Wqkv∘ln_g (col-scaled),
//   u = Wqkv·ln_g, c = Wqkv·ln_b + bqkv, r=rstd, m=mu per (token,expert) row.

using bf16   = __bf16;
using bf16x8 = __attribute__((ext_vector_type(8))) __bf16;
using f32x16 = __attribute__((ext_vector_type(16))) float;

// ---------------------------------------------------------------------------
// Split fp32 matrix (R x K, ld=ldin) into hi/lo bf16, zero-padded to Rp x Kp.
// Optional per-column scale (Wg = Wqkv * ln_g).
__global__ __launch_bounds__(256) void split_pad(
    const float* __restrict__ in, int R, int K, int ldin,
    bf16* __restrict__ oh, bf16* __restrict__ ol, int Rp, int Kp,
    const float* __restrict__ cs)
{
    const int total8 = (Rp * Kp) >> 3;
    for (int idx = blockIdx.x * 256 + threadIdx.x; idx < total8;
         idx += gridDim.x * 256) {
        const int r  = (idx << 3) / Kp;
        const int k8 = (idx << 3) - r * Kp;
        float v[8];
#pragma unroll
        for (int j = 0; j < 8; ++j) {
            const int k = k8 + j;
            float x = (r < R && k < K) ? in[(size_t)r * ldin + k] : 0.f;
            if (cs && k < K) x *= cs[k];
            v[j] = x;
        }
        bf16x8 h8, l8;
#pragma unroll
        for (int j = 0; j < 8; ++j) {
            const bf16 h = (bf16)v[j];
            h8[j] = h;
            l8[j] = (bf16)(v[j] - (float)h);
        }
        *(bf16x8*)(oh + (size_t)r * Kp + k8) = h8;
        *(bf16x8*)(ol + (size_t)r * Kp + k8) = l8;
    }
}

// u[n] = sum_k Wqkv[n,k]*g[k];  c[n] = sum_k Wqkv[n,k]*b[k] + bqkv[n]
__global__ __launch_bounds__(256) void qkv_uc(
    const float* __restrict__ W, const float* __restrict__ g,
    const float* __restrict__ b, const float* __restrict__ bq,
    float* __restrict__ u, float* __restrict__ c)
{
    const int n = blockIdx.x * 4 + (threadIdx.x >> 6);
    const int lane = threadIdx.x & 63;
    float su = 0.f, sc = 0.f;
#pragma unroll
    for (int j = 0; j < 8; ++j) {
        const int k = lane * 8 + j;
        const float w = W[(size_t)n * 512 + k];
        su += w * g[k];
        sc += w * b[k];
    }
#pragma unroll
    for (int o = 32; o > 0; o >>= 1) { su += __shfl_xor(su, o); sc += __shfl_xor(sc, o); }
    if (lane == 0) { u[n] = su; c[n] = sc + bq[n]; }
}

// Per-row LN stats from reconstructed S = Sh + Sl. One wave per 512-row.
__global__ __launch_bounds__(256) void ln_stats_bf(
    const bf16* __restrict__ Sh, const bf16* __restrict__ Sl,
    float* __restrict__ mu, float* __restrict__ rstd)
{
    const int row = blockIdx.x * 4 + (threadIdx.x >> 6);
    const int lane = threadIdx.x & 63;
    const bf16x8 h = *(const bf16x8*)(Sh + (size_t)row * 512 + lane * 8);
    const bf16x8 l = *(const bf16x8*)(Sl + (size_t)row * 512 + lane * 8);
    float s = 0.f, q = 0.f;
#pragma unroll
    for (int j = 0; j < 8; ++j) {
        const float v = (float)h[j] + (float)l[j];
        s += v; q += v * v;
    }
#pragma unroll
    for (int o = 32; o > 0; o >>= 1) { s += __shfl_xor(s, o); q += __shfl_xor(q, o); }
    if (lane == 0) {
        const float m = s * (1.f / 512.f);
        mu[row] = m;
        rstd[row] = rsqrtf(q * (1.f / 512.f) - m * m + 1e-5f);
    }
}

// ---------------------------------------------------------------------------
// GEMM C[m,n] = sum_k A[m,k]*B[n,k], operands pre-split hi/lo bf16, padded so
// every staged row/col is in-bounds. 128x128 tile, BK=32, 4 waves.
// LDS layout (r2-proven): 128 rows x 128B, row = [hi k0..k31 | lo k0..k31],
// byte offsets XORed with (row&7)<<4. Register staging: bf16x8 global loads +
// ds_write_b128 (no global_load_lds).
// bf16x3 per k-tile: acc += Ah*Bh + Ah*Bl + Al*Bh.
// MODE 0: split-write Ch/Cl              (K1: S = x @ Win^T)
// MODE 1: Cf = r*acc - r*m*u[n] + c[n]   (K3: fused-LN QKV)
// MODE 2: v = acc + bias[n] + (Ch+Cl); split-write back (K4b: S += ctx@Wo^T+bo)
// MODE 3: Cf = acc + resid               (K5: out = S@Wout^T + x)
template <int MODE>
__global__ __launch_bounds__(256, 2) void gemm_hilo(
    const bf16* __restrict__ Ah, const bf16* __restrict__ Al, int lda,
    const bf16* __restrict__ Bh, const bf16* __restrict__ Bl, int ldb,
    int Kp, int N,
    float* __restrict__ Cf, int ldc,
    bf16* __restrict__ Ch, bf16* __restrict__ Cl,
    const float* __restrict__ muP, const float* __restrict__ rsP,
    const float* __restrict__ uV, const float* __restrict__ cV,
    const float* __restrict__ bias,
    const float* __restrict__ resid, int ldr)
{
    __shared__ __align__(16) char lA[128 * 128];
    __shared__ __align__(16) char lB[128 * 128];

    const int tid = threadIdx.x;
    const int m0 = blockIdx.x * 128, n0 = blockIdx.y * 128;

    // --- staging coords: thread t covers row t>>1, bytes [(t&1)*32, +32) ---
    const int srow = tid >> 1;
    const int sh16 = (tid & 1) << 5;          // 0 or 32
    const int swr  = (srow & 7) << 4;
    const size_t ldaB = (size_t)lda * 2, ldbB = (size_t)ldb * 2;
    const char* gAh = (const char*)Ah + (size_t)(m0 + srow) * ldaB + sh16;
    const char* gAl = (const char*)Al + (size_t)(m0 + srow) * ldaB + sh16;
    const char* gBh = (const char*)Bh + (size_t)(n0 + srow) * ldbB + sh16;
    const char* gBl = (const char*)Bl + (size_t)(n0 + srow) * ldbB + sh16;
    char* wA = lA + srow * 128;
    char* wB = lB + srow * 128;

    // --- compute coords: wave (wr,wc) owns 64x64; 2x2 frags of 32x32 ---
    const int w = tid >> 6, lane = tid & 63;
    const int wr = w >> 1, wc = w & 1;
    const int lrow = lane & 31, lkg = lane >> 5;
    const int swz = (lrow & 7) << 4;

    f32x16 acc[2][2];
#pragma unroll
    for (int i = 0; i < 2; ++i)
#pragma unroll
        for (int j = 0; j < 2; ++j)
#pragma unroll
            for (int r = 0; r < 16; ++r) acc[i][j][r] = 0.f;

#pragma unroll 1
    for (int kb = 0; kb < Kp * 2; kb += 64) {   // kb = byte offset along K
        const bf16x8 va0 = *(const bf16x8*)(gAh + kb);
        const bf16x8 va1 = *(const bf16x8*)(gAh + kb + 16);
        const bf16x8 va2 = *(const bf16x8*)(gAl + kb);
        const bf16x8 va3 = *(const bf16x8*)(gAl + kb + 16);
        const bf16x8 vb0 = *(const bf16x8*)(gBh + kb);
        const bf16x8 vb1 = *(const bf16x8*)(gBh + kb + 16);
        const bf16x8 vb2 = *(const bf16x8*)(gBl + kb);
        const bf16x8 vb3 = *(const bf16x8*)(gBl + kb + 16);
        __syncthreads();                         // prev tile reads done
        *(bf16x8*)(wA + ((sh16) ^ swr))           = va0;
        *(bf16x8*)(wA + ((sh16 + 16) ^ swr))      = va1;
        *(bf16x8*)(wA + ((64 + sh16) ^ swr))      = va2;
        *(bf16x8*)(wA + ((64 + sh16 + 16) ^ swr)) = va3;
        *(bf16x8*)(wB + ((sh16) ^ swr))           = vb0;
        *(bf16x8*)(wB + ((sh16 + 16) ^ swr))      = vb1;
        *(bf16x8*)(wB + ((64 + sh16) ^ swr))      = vb2;
        *(bf16x8*)(wB + ((64 + sh16 + 16) ^ swr)) = vb3;
        __syncthreads();                         // writes visible

        bf16x8 ah[2][2], al[2][2], bh[2][2], bl[2][2];  // [frag][kgroup]
#pragma unroll
        for (int f = 0; f < 2; ++f) {
            const char* baA = lA + (wr * 64 + f * 32 + lrow) * 128;
            const char* baB = lB + (wc * 64 + f * 32 + lrow) * 128;
#pragma unroll
            for (int g = 0; g < 2; ++g) {
                const int off = g * 32 + lkg * 16;
                ah[f][g] = *(const bf16x8*)(baA + ((off) ^ swz));
                al[f][g] = *(const bf16x8*)(baA + ((64 + off) ^ swz));
                bh[f][g] = *(const bf16x8*)(baB + ((off) ^ swz));
                bl[f][g] = *(const bf16x8*)(baB + ((64 + off) ^ swz));
            }
        }
#pragma unroll
        for (int g = 0; g < 2; ++g)
#pragma unroll
            for (int fm = 0; fm < 2; ++fm)
#pragma unroll
                for (int fn = 0; fn < 2; ++fn) {
                    acc[fm][fn] = __builtin_amdgcn_mfma_f32_32x32x16_bf16(
                        ah[fm][g], bh[fn][g], acc[fm][fn], 0, 0, 0);
                    acc[fm][fn] = __builtin_amdgcn_mfma_f32_32x32x16_bf16(
                        ah[fm][g], bl[fn][g], acc[fm][fn], 0, 0, 0);
                    acc[fm][fn] = __builtin_amdgcn_mfma_f32_32x32x16_bf16(
                        al[fm][g], bh[fn][g], acc[fm][fn], 0, 0, 0);
                }
        __syncthreads();                         // reads done before restage
    }

    // --- epilogue. C/D map: col=lane&31, row=(r&3)+8*(r>>2)+4*(lane>>5) ---
#pragma unroll
    for (int fm = 0; fm < 2; ++fm)
#pragma unroll
        for (int fn = 0; fn < 2; ++fn) {
            const int gc = n0 + wc * 64 + fn * 32 + lrow;
            if (gc < N) {
#pragma unroll
                for (int r = 0; r < 16; ++r) {
                    const int gm = m0 + wr * 64 + fm * 32 + (r & 3) + 8 * (r >> 2) + 4 * lkg;
                    float v = acc[fm][fn][r];
                    const size_t ci = (size_t)gm * ldc + gc;
                    if (MODE == 0) {
                        const bf16 h = (bf16)v;
                        Ch[ci] = h;
                        Cl[ci] = (bf16)(v - (float)h);
                    } else if (MODE == 1) {
                        const float rr = rsP[gm], mm = muP[gm];
                        Cf[ci] = rr * v - rr * mm * uV[gc] + cV[gc];
                    } else if (MODE == 2) {
                        v += bias[gc] + (float)Ch[ci] + (float)Cl[ci];
                        const bf16 h = (bf16)v;
                        Ch[ci] = h;
                        Cl[ci] = (bf16)(v - (float)h);
                    } else {
                        Cf[ci] = v + resid[(size_t)gm * ldr + gc];
                    }
                }
            }
        }
}

// ---------------------------------------------------------------------------
// One wave per token: 4x4 DAG-masked MHA over experts, 8 heads of 64.
// Row 0 softmax is singleton -> ctx0 = v0. Output split to hi/lo bf16.
__global__ __launch_bounds__(256) void attn_refine(
    const float* __restrict__ QKV, bf16* __restrict__ Ch, bf16* __restrict__ Cl,
    int ntok)
{
    const int w = threadIdx.x >> 6;
    const int lane = threadIdx.x & 63;
    const int t = blockIdx.x * 4 + w;
    if (t >= ntok) return;
    const float* __restrict__ base = QKV + (size_t)t * 4 * 1536;
    const size_t cb = (size_t)t * 4 * 512;
#pragma unroll
    for (int h = 0; h < 8; ++h) {
        const int off = h * 64 + lane;
        const float q1 = base[1536 + off];
        const float q2 = base[2 * 1536 + off];
        const float q3 = base[3 * 1536 + off];
        const float k0 = base[512 + off];
        const float k1 = base[1536 + 512 + off];
        const float k2 = base[2 * 1536 + 512 + off];
        const float k3 = base[3 * 1536 + 512 + off];
        const float v0 = base[1024 + off];
        const float v1 = base[1536 + 1024 + off];
        const float v2 = base[2 * 1536 + 1024 + off];
        const float v3 = base[3 * 1536 + 1024 + off];
        float s10 = q1 * k0, s11 = q1 * k1;
        float s20 = q2 * k0, s21 = q2 * k1, s22 = q2 * k2;
        float s30 = q3 * k0, s31 = q3 * k1, s32 = q3 * k2, s33 = q3 * k3;
#pragma unroll
        for (int o = 32; o > 0; o >>= 1) {
            s10 += __shfl_xor(s10, o); s11 += __shfl_xor(s11, o);
            s20 += __shfl_xor(s20, o); s21 += __shfl_xor(s21, o); s22 += __shfl_xor(s22, o);
            s30 += __shfl_xor(s30, o); s31 += __shfl_xor(s31, o);
            s32 += __shfl_xor(s32, o); s33 += __shfl_xor(s33, o);
        }
        const float sc = 0.125f;
        s10 *= sc; s11 *= sc;
        s20 *= sc; s21 *= sc; s22 *= sc;
        s30 *= sc; s31 *= sc; s32 *= sc; s33 *= sc;

        const float m1 = fmaxf(s10, s11);
        const float e10 = expf(s10 - m1), e11 = expf(s11 - m1);
        const float r1 = 1.f / (e10 + e11);
        const float m2 = fmaxf(fmaxf(s20, s21), s22);
        const float e20 = expf(s20 - m2), e21 = expf(s21 - m2), e22 = expf(s22 - m2);
        const float r2 = 1.f / (e20 + e21 + e22);
        const float m3 = fmaxf(fmaxf(s30, s31), fmaxf(s32, s33));
        const float e30 = expf(s30 - m3), e31 = expf(s31 - m3);
        const float e32 = expf(s32 - m3), e33 = expf(s33 - m3);
        const float r3 = 1.f / (e30 + e31 + e32 + e33);

        const float c0 = v0;
        const float c1 = (e10 * v0 + e11 * v1) * r1;
        const float c2 = (e20 * v0 + e21 * v1 + e22 * v2) * r2;
        const float c3 = (e30 * v0 + e31 * v1 + e32 * v2 + e33 * v3) * r3;
#pragma unroll
        for (int e = 0; e < 4; ++e) {
            const float cv = (e == 0) ? c0 : (e == 1) ? c1 : (e == 2) ? c2 : c3;
            const bf16 hh = (bf16)cv;
            Ch[cb + e * 512 + off] = hh;
            Cl[cb + e * 512 + off] = (bf16)(cv - (float)hh);
        }
    }
}

// ---------------------------------------------------------------------------
extern "C" void kernel_launch(void* const* d_in, const int* in_sizes, int n_in,
                              void* d_out, int out_size, void* d_ws, size_t ws_size,
                              hipStream_t stream)
{
    (void)in_sizes; (void)n_in; (void)out_size; (void)ws_size;
    const float* x[4]    = {(const float*)d_in[0], (const float*)d_in[3],
                            (const float*)d_in[6], (const float*)d_in[9]};
    const float* Win[4]  = {(const float*)d_in[1], (const float*)d_in[4],
                            (const float*)d_in[7], (const float*)d_in[10]};
    const float* Wout[4] = {(const float*)d_in[2], (const float*)d_in[5],
                            (const float*)d_in[8], (const float*)d_in[11]};
    const float* ln_g = (const float*)d_in[12];
    const float* ln_b = (const float*)d_in[13];
    const float* Wqkv = (const float*)d_in[14];
    const float* bqkv = (const float*)d_in[15];
    const float* Wo   = (const float*)d_in[16];
    const float* bo   = (const float*)d_in[17];
    float* out = (float*)d_out;

    const int dE[4]  = {128, 128, 1006, 104};
    const int KpE[4] = {128, 128, 1024, 128};   // K padded to x32
    const int NTOK = 16384, ROWS = 65536;
    const int TPC = 1024, XR = 4096;            // FIXED chunk sizes (no branches)

    // ---- ws carve-out (fixed layout, 178.3 MB total; r2 proved >= 201.8 MB) ----
    char* p = (char*)d_ws;
    auto alloc = [&](size_t bytes) -> char* {
        char* q = p; p += (bytes + 255) & ~(size_t)255; return q;
    };
    bf16* Sh = (bf16*)alloc((size_t)ROWS * 512 * 2);
    bf16* Sl = (bf16*)alloc((size_t)ROWS * 512 * 2);
    bf16 *Wih[4], *Wil[4], *Woth[4], *Wotl[4];
    for (int e = 0; e < 4; ++e) {
        Wih[e] = (bf16*)alloc((size_t)512 * KpE[e] * 2);
        Wil[e] = (bf16*)alloc((size_t)512 * KpE[e] * 2);
    }
    bf16* Wgh = (bf16*)alloc((size_t)1536 * 512 * 2);
    bf16* Wgl = (bf16*)alloc((size_t)1536 * 512 * 2);
    bf16* Woh = (bf16*)alloc((size_t)512 * 512 * 2);
    bf16* Wol = (bf16*)alloc((size_t)512 * 512 * 2);
    for (int e = 0; e < 4; ++e) {
        Woth[e] = (bf16*)alloc((size_t)KpE[e] * 512 * 2);
        Wotl[e] = (bf16*)alloc((size_t)KpE[e] * 512 * 2);
    }
    float* mu   = (float*)alloc((size_t)ROWS * 4);
    float* rstd = (float*)alloc((size_t)ROWS * 4);
    float* uV   = (float*)alloc(1536 * 4);
    float* cV   = (float*)alloc(1536 * 4);
    char* U = p;   // scratch region, max concurrent use 33.6 MB

    auto splitLaunch = [&](const float* in, int R, int K, int ldin,
                           bf16* oh, bf16* ol, int Rp, int Kp, const float* cs) {
        const int total8 = (Rp * Kp) >> 3;
        int blocks = (total8 + 255) / 256; if (blocks > 4096) blocks = 4096;
        split_pad<<<blocks, 256, 0, stream>>>(in, R, K, ldin, oh, ol, Rp, Kp, cs);
    };

    // ---- weight prep (in-graph, every call) ----
    for (int e = 0; e < 4; ++e)
        splitLaunch(Win[e], 512, dE[e], dE[e], Wih[e], Wil[e], 512, KpE[e], nullptr);
    splitLaunch(Wqkv, 1536, 512, 512, Wgh, Wgl, 1536, 512, ln_g);
    splitLaunch(Wo, 512, 512, 512, Woh, Wol, 512, 512, nullptr);
    for (int e = 0; e < 4; ++e)
        splitLaunch(Wout[e], dE[e], 512, 512, Woth[e], Wotl[e], KpE[e], 512, nullptr);
    qkv_uc<<<1536 / 4, 256, 0, stream>>>(Wqkv, ln_g, ln_b, bqkv, uV, cV);

    // ---- K1: per-expert input projections -> Sh/Sl (row = t*4+e via ldc=2048) ----
    bf16* xh = (bf16*)U;
    for (int e = 0; e < 4; ++e) {
        const int rowsPer = (e == 2) ? XR : NTOK;
        bf16* xl = xh + (size_t)rowsPer * KpE[e];
        for (int t0 = 0; t0 < NTOK; t0 += rowsPer) {
            splitLaunch(x[e] + (size_t)t0 * dE[e], rowsPer, dE[e], dE[e],
                        xh, xl, rowsPer, KpE[e], nullptr);
            gemm_hilo<0><<<dim3(rowsPer / 128, 4), 256, 0, stream>>>(
                xh, xl, KpE[e], Wih[e], Wil[e], KpE[e], KpE[e], 512,
                nullptr, 2048, Sh + (size_t)t0 * 2048 + e * 512,
                Sl + (size_t)t0 * 2048 + e * 512,
                nullptr, nullptr, nullptr, nullptr, nullptr, nullptr, 0);
        }
    }

    // ---- K2: LN stats ----
    ln_stats_bf<<<ROWS / 4, 256, 0, stream>>>(Sh, Sl, mu, rstd);

    // ---- chunked QKV -> attention -> Wo (+residual into Sh/Sl) ----
    const int NCH = NTOK / TPC, RPC = TPC * 4;
    float* QKVc = (float*)U;
    bf16* CTXh  = (bf16*)(U + (size_t)RPC * 1536 * 4);
    bf16* CTXl  = CTXh + (size_t)RPC * 512;
    for (int c = 0; c < NCH; ++c) {
        const size_t rb = (size_t)c * RPC;
        gemm_hilo<1><<<dim3(RPC / 128, 12), 256, 0, stream>>>(
            Sh + rb * 512, Sl + rb * 512, 512, Wgh, Wgl, 512, 512, 1536,
            QKVc, 1536, nullptr, nullptr,
            mu + rb, rstd + rb, uV, cV, nullptr, nullptr, 0);
        attn_refine<<<TPC / 4, 256, 0, stream>>>(QKVc, CTXh, CTXl, TPC);
        gemm_hilo<2><<<dim3(RPC / 128, 4), 256, 0, stream>>>(
            CTXh, CTXl, 512, Woh, Wol, 512, 512, 512,
            nullptr, 512, Sh + rb * 512, Sl + rb * 512,
            nullptr, nullptr, nullptr, nullptr, bo, nullptr, 0);
    }

    // ---- K5: per-expert output projections + input residual -> out ----
    size_t off = 0;
    for (int e = 0; e < 4; ++e) {
        gemm_hilo<3><<<dim3(NTOK / 128, KpE[e] / 128), 256, 0, stream>>>(
            Sh + e * 512, Sl + e * 512, 2048, Woth[e], Wotl[e], 512, 512, dE[e],
            out + off, dE[e], nullptr, nullptr,
            nullptr, nullptr, nullptr, nullptr, nullptr, x[e], dE[e]);
        off += (size_t)NTOK * dE[e];
    }
}

// Round 5
// 1362.013 us; speedup vs baseline: 1.5487x; 1.5487x over previous
//
#include <hip/hip_runtime.h>
#include <hip/hip_bf16.h>
#include <stdint.h>

// CrossExpertRefinement on MI355X — round 5.
// bf16x3 split-GEMM, plane-tiled hi/lo operands, global_load_lds double-buffer
// pipeline with counted vmcnt(8), source-side swizzle (linear LDS dest),
// bijective XCD-chunked block order, fused LN / bias / residual epilogues.
//
// Plane-tiled operand layout: element (row,k) hi byte =
//   base + ((2*(k>>5)+0)*R + row0 + row*rstride)*64 + (k&31)*2 ; lo plane +R*64.

using bf16   = __bf16;
using bf16x8 = __attribute__((ext_vector_type(8))) __bf16;
using f32x16 = __attribute__((ext_vector_type(16))) float;

#define GLOAD16(g, l) __builtin_amdgcn_global_load_lds(                        \
    (const __attribute__((address_space(1))) unsigned int*)(g),                \
    (__attribute__((address_space(3))) unsigned int*)(l), 16, 0, 0)

struct Op { const char* base; int R; int row0; int rstride; };

// ---------------------------------------------------------------------------
// fp32 (R x K, ld=ldin) -> plane-tiled hi/lo bf16, zero-padded to Rp x Kp.
__global__ __launch_bounds__(256) void split_tiled(
    const float* __restrict__ in, int R, int K, int ldin,
    char* __restrict__ outb, int Rp, int Kp, const float* __restrict__ cs)
{
    const size_t ps = (size_t)Rp * 64;
    const int total8 = (Rp * Kp) >> 3;
    for (int idx = blockIdx.x * 256 + threadIdx.x; idx < total8;
         idx += gridDim.x * 256) {
        const int r  = (idx << 3) / Kp;
        const int k8 = (idx << 3) - r * Kp;
        float v[8];
#pragma unroll
        for (int j = 0; j < 8; ++j) {
            const int k = k8 + j;
            float x = (r < R && k < K) ? in[(size_t)r * ldin + k] : 0.f;
            if (cs && k < K) x *= cs[k];
            v[j] = x;
        }
        bf16x8 h8, l8;
#pragma unroll
        for (int j = 0; j < 8; ++j) {
            const bf16 h = (bf16)v[j];
            h8[j] = h;
            l8[j] = (bf16)(v[j] - (float)h);
        }
        char* hp = outb + (size_t)(2 * (k8 >> 5)) * ps + (size_t)r * 64 + (k8 & 31) * 2;
        *(bf16x8*)hp = h8;
        *(bf16x8*)(hp + ps) = l8;
    }
}

// u[n] = Wqkv[n,:]·ln_g ; c[n] = Wqkv[n,:]·ln_b + bqkv[n]
__global__ __launch_bounds__(256) void qkv_uc(
    const float* __restrict__ W, const float* __restrict__ g,
    const float* __restrict__ b, const float* __restrict__ bq,
    float* __restrict__ u, float* __restrict__ c)
{
    const int n = blockIdx.x * 4 + (threadIdx.x >> 6);
    const int lane = threadIdx.x & 63;
    float su = 0.f, sc = 0.f;
#pragma unroll
    for (int j = 0; j < 8; ++j) {
        const int k = lane * 8 + j;
        const float w = W[(size_t)n * 512 + k];
        su += w * g[k];
        sc += w * b[k];
    }
#pragma unroll
    for (int o = 32; o > 0; o >>= 1) { su += __shfl_xor(su, o); sc += __shfl_xor(sc, o); }
    if (lane == 0) { u[n] = su; c[n] = sc + bq[n]; }
}

// Per-row LN stats from plane-tiled S (R=65536, Kp=512). One wave per row.
__global__ __launch_bounds__(256) void ln_stats_t(
    const char* __restrict__ St, int R, float* __restrict__ mu, float* __restrict__ rstd)
{
    const int row = blockIdx.x * 4 + (threadIdx.x >> 6);
    const int lane = threadIdx.x & 63;
    const int kt = lane >> 2, qq = lane & 3;
    const size_t ps = (size_t)R * 64;
    const char* hp = St + (size_t)(2 * kt) * ps + (size_t)row * 64 + qq * 16;
    const bf16x8 h = *(const bf16x8*)hp;
    const bf16x8 l = *(const bf16x8*)(hp + ps);
    float s = 0.f, q = 0.f;
#pragma unroll
    for (int j = 0; j < 8; ++j) {
        const float v = (float)h[j] + (float)l[j];
        s += v; q += v * v;
    }
#pragma unroll
    for (int o = 32; o > 0; o >>= 1) { s += __shfl_xor(s, o); q += __shfl_xor(q, o); }
    if (lane == 0) {
        const float m = s * (1.f / 512.f);
        mu[row] = m;
        rstd[row] = rsqrtf(q * (1.f / 512.f) - m * m + 1e-5f);
    }
}

// ---------------------------------------------------------------------------
// GEMM C[m,n] = sum_k A[m,k]*B[n,k]; A,B plane-tiled hi/lo bf16 (padded).
// 128x128 tile, BK=32, 4 waves, 32x32x16 MFMA, bf16x3 (Ah*Bh+Ah*Bl+Al*Bh).
// global_load_lds into 2-buffer LDS; counted vmcnt(8); raw barriers.
// MODE 0: split-write C into plane-tiled Ct              (K1)
// MODE 1: Cq[m,n] = bf16(r*acc - r*mu*u[n] + c[n])       (K3 fused-LN QKV)
// MODE 2: v = acc + bias[n] + Ct(hi+lo); split rewrite   (K4b residual accum)
// MODE 3: Cf[m,n] = acc + resid[m,n]                     (K5)
template <int MODE>
__global__ __launch_bounds__(256, 2) void gemm_ht(
    Op A, Op B, int nbx, int Kp, int N,
    float* __restrict__ Cf, int ldc,
    bf16* __restrict__ Cq,
    char* __restrict__ Ct, int CtR, int Ctrow0, int Ctstride,
    const float* __restrict__ muP, const float* __restrict__ rsP,
    const float* __restrict__ uV, const float* __restrict__ cV,
    const float* __restrict__ bias,
    const float* __restrict__ resid, int ldr)
{
    __shared__ __align__(16) char lds[2][2][16384];   // [buf][A|B][128 rows x 128B]
    const int tid = threadIdx.x, w = tid >> 6, lane = tid & 63;

    // bijective XCD remap (m204), y-major bands: consecutive wg share n0.
    const int nwg = gridDim.x;
    const int qd = nwg >> 3, rm = nwg & 7;
    const int xc = blockIdx.x & 7, pos = blockIdx.x >> 3;
    const int wg = (xc < rm ? xc * (qd + 1) : rm * (qd + 1) + (xc - rm) * qd) + pos;
    const int m0 = (wg % nbx) * 128, n0 = (wg / nbx) * 128;

    // staging sources: instr i covers rows w*32+i*8 .. +8; lane -> row r8, part p8.
    // source swizzle pp = p8 ^ r8 (involution with read-side XOR (lrow&7)<<4).
    const int p8 = lane & 7, r8 = lane >> 3;
    const int pp = p8 ^ r8;
    const size_t psA = (size_t)A.R * 64, psB = (size_t)B.R * 64;
    const size_t lpA = (size_t)(pp >> 2) * psA + (size_t)(pp & 3) * 16;
    const size_t lpB = (size_t)(pp >> 2) * psB + (size_t)(pp & 3) * 16;
    const char* sA0 = A.base + lpA + (size_t)(A.row0 + (size_t)(m0 + w * 32      + r8) * A.rstride) * 64;
    const char* sA1 = A.base + lpA + (size_t)(A.row0 + (size_t)(m0 + w * 32 + 8  + r8) * A.rstride) * 64;
    const char* sA2 = A.base + lpA + (size_t)(A.row0 + (size_t)(m0 + w * 32 + 16 + r8) * A.rstride) * 64;
    const char* sA3 = A.base + lpA + (size_t)(A.row0 + (size_t)(m0 + w * 32 + 24 + r8) * A.rstride) * 64;
    const char* sB0 = B.base + lpB + (size_t)(B.row0 + (size_t)(n0 + w * 32      + r8) * B.rstride) * 64;
    const char* sB1 = B.base + lpB + (size_t)(B.row0 + (size_t)(n0 + w * 32 + 8  + r8) * B.rstride) * 64;
    const char* sB2 = B.base + lpB + (size_t)(B.row0 + (size_t)(n0 + w * 32 + 16 + r8) * B.rstride) * 64;
    const char* sB3 = B.base + lpB + (size_t)(B.row0 + (size_t)(n0 + w * 32 + 24 + r8) * B.rstride) * 64;

#define STAGE(buf, kt) do {                                                    \
        const size_t oA = (size_t)(2 * (kt)) * psA;                            \
        const size_t oB = (size_t)(2 * (kt)) * psB;                            \
        char* dA = &lds[buf][0][(w * 32) * 128];                               \
        char* dB = &lds[buf][1][(w * 32) * 128];                               \
        GLOAD16(sA0 + oA, dA);        GLOAD16(sA1 + oA, dA + 1024);            \
        GLOAD16(sA2 + oA, dA + 2048); GLOAD16(sA3 + oA, dA + 3072);            \
        GLOAD16(sB0 + oB, dB);        GLOAD16(sB1 + oB, dB + 1024);            \
        GLOAD16(sB2 + oB, dB + 2048); GLOAD16(sB3 + oB, dB + 3072);            \
    } while (0)

    // compute coords (r4-proven): wave (wr,wc) owns 64x64 = 2x2 of 32x32.
    const int wr = w >> 1, wc = w & 1;
    const int lrow = lane & 31, lkg = lane >> 5;
    const int swz = (lrow & 7) << 4;

    f32x16 acc[2][2];
#pragma unroll
    for (int i = 0; i < 2; ++i)
#pragma unroll
        for (int j = 0; j < 2; ++j)
#pragma unroll
            for (int r = 0; r < 16; ++r) acc[i][j][r] = 0.f;

    const int nk = Kp >> 5;
    STAGE(0, 0);
    int cur = 0;
#pragma unroll 1
    for (int kt = 0; kt < nk; ++kt) {
        const int ktn = (kt + 1 < nk) ? kt + 1 : kt;   // clamp: wasted L2-hot reload
        STAGE(cur ^ 1, ktn);
        __builtin_amdgcn_sched_barrier(0);
        asm volatile("s_waitcnt vmcnt(8)" ::: "memory");   // cur's 8 landed
        __builtin_amdgcn_sched_barrier(0);
        __builtin_amdgcn_s_barrier();
        __builtin_amdgcn_sched_barrier(0);
        {
            bf16x8 ah[2][2], al[2][2], bh[2][2], bl[2][2];
#pragma unroll
            for (int f = 0; f < 2; ++f) {
                const char* baA = &lds[cur][0][(wr * 64 + f * 32 + lrow) * 128];
                const char* baB = &lds[cur][1][(wc * 64 + f * 32 + lrow) * 128];
#pragma unroll
                for (int g = 0; g < 2; ++g) {
                    const int off = g * 32 + lkg * 16;
                    ah[f][g] = *(const bf16x8*)(baA + ((off) ^ swz));
                    al[f][g] = *(const bf16x8*)(baA + ((64 + off) ^ swz));
                    bh[f][g] = *(const bf16x8*)(baB + ((off) ^ swz));
                    bl[f][g] = *(const bf16x8*)(baB + ((64 + off) ^ swz));
                }
            }
#pragma unroll
            for (int g = 0; g < 2; ++g)
#pragma unroll
                for (int fm = 0; fm < 2; ++fm)
#pragma unroll
                    for (int fn = 0; fn < 2; ++fn) {
                        acc[fm][fn] = __builtin_amdgcn_mfma_f32_32x32x16_bf16(
                            ah[fm][g], bh[fn][g], acc[fm][fn], 0, 0, 0);
                        acc[fm][fn] = __builtin_amdgcn_mfma_f32_32x32x16_bf16(
                            ah[fm][g], bl[fn][g], acc[fm][fn], 0, 0, 0);
                        acc[fm][fn] = __builtin_amdgcn_mfma_f32_32x32x16_bf16(
                            al[fm][g], bh[fn][g], acc[fm][fn], 0, 0, 0);
                    }
        }
        __builtin_amdgcn_sched_barrier(0);
        __builtin_amdgcn_s_barrier();                  // reads done before overwrite
        cur ^= 1;
    }
    asm volatile("s_waitcnt vmcnt(0)" ::: "memory");   // drain tail DMAs
#undef STAGE

    // epilogue. C/D map (verified r2/r4): col=lane&31, row=(r&3)+8*(r>>2)+4*(lane>>5)
    const size_t psC = (size_t)CtR * 64;
#pragma unroll
    for (int fm = 0; fm < 2; ++fm)
#pragma unroll
        for (int fn = 0; fn < 2; ++fn) {
            const int gc = n0 + wc * 64 + fn * 32 + lrow;
            if (gc < N) {
#pragma unroll
                for (int r = 0; r < 16; ++r) {
                    const int gm = m0 + wr * 64 + fm * 32 + (r & 3) + 8 * (r >> 2) + 4 * lkg;
                    float v = acc[fm][fn][r];
                    if (MODE == 0 || MODE == 2) {
                        char* hp = Ct + (size_t)(2 * (gc >> 5)) * psC
                                 + (size_t)(Ctrow0 + (size_t)gm * Ctstride) * 64 + (gc & 31) * 2;
                        if (MODE == 2)
                            v += bias[gc] + (float)*(const bf16*)hp + (float)*(const bf16*)(hp + psC);
                        const bf16 h = (bf16)v;
                        *(bf16*)hp = h;
                        *(bf16*)(hp + psC) = (bf16)(v - (float)h);
                    } else if (MODE == 1) {
                        const float rr = rsP[gm], mm = muP[gm];
                        Cq[(size_t)gm * 1536 + gc] = (bf16)(rr * v - rr * mm * uV[gc] + cV[gc]);
                    } else {
                        Cf[(size_t)gm * ldc + gc] = v + resid[(size_t)gm * ldr + gc];
                    }
                }
            }
        }
}

// ---------------------------------------------------------------------------
// One wave per token: 4x4 DAG-masked MHA, 8 heads of 64. qkv in bf16 row-major
// [4*ntok][1536]; ctx written plane-tiled hi/lo (R = 4*ntok).
__global__ __launch_bounds__(256) void attn_refine(
    const bf16* __restrict__ QKV, char* __restrict__ Ct, int R, int ntok)
{
    const int w = threadIdx.x >> 6;
    const int lane = threadIdx.x & 63;
    const int t = blockIdx.x * 4 + w;
    if (t >= ntok) return;
    const bf16* __restrict__ base = QKV + (size_t)t * 4 * 1536;
    const size_t ps = (size_t)R * 64;
#pragma unroll
    for (int h = 0; h < 8; ++h) {
        const int off = h * 64 + lane;
        const float q1 = (float)base[1536 + off];
        const float q2 = (float)base[2 * 1536 + off];
        const float q3 = (float)base[3 * 1536 + off];
        const float k0 = (float)base[512 + off];
        const float k1 = (float)base[1536 + 512 + off];
        const float k2 = (float)base[2 * 1536 + 512 + off];
        const float k3 = (float)base[3 * 1536 + 512 + off];
        const float v0 = (float)base[1024 + off];
        const float v1 = (float)base[1536 + 1024 + off];
        const float v2 = (float)base[2 * 1536 + 1024 + off];
        const float v3 = (float)base[3 * 1536 + 1024 + off];
        float s10 = q1 * k0, s11 = q1 * k1;
        float s20 = q2 * k0, s21 = q2 * k1, s22 = q2 * k2;
        float s30 = q3 * k0, s31 = q3 * k1, s32 = q3 * k2, s33 = q3 * k3;
#pragma unroll
        for (int o = 32; o > 0; o >>= 1) {
            s10 += __shfl_xor(s10, o); s11 += __shfl_xor(s11, o);
            s20 += __shfl_xor(s20, o); s21 += __shfl_xor(s21, o); s22 += __shfl_xor(s22, o);
            s30 += __shfl_xor(s30, o); s31 += __shfl_xor(s31, o);
            s32 += __shfl_xor(s32, o); s33 += __shfl_xor(s33, o);
        }
        const float sc = 0.125f;
        s10 *= sc; s11 *= sc;
        s20 *= sc; s21 *= sc; s22 *= sc;
        s30 *= sc; s31 *= sc; s32 *= sc; s33 *= sc;

        const float m1 = fmaxf(s10, s11);
        const float e10 = expf(s10 - m1), e11 = expf(s11 - m1);
        const float r1 = 1.f / (e10 + e11);
        const float m2 = fmaxf(fmaxf(s20, s21), s22);
        const float e20 = expf(s20 - m2), e21 = expf(s21 - m2), e22 = expf(s22 - m2);
        const float r2 = 1.f / (e20 + e21 + e22);
        const float m3 = fmaxf(fmaxf(s30, s31), fmaxf(s32, s33));
        const float e30 = expf(s30 - m3), e31 = expf(s31 - m3);
        const float e32 = expf(s32 - m3), e33 = expf(s33 - m3);
        const float r3 = 1.f / (e30 + e31 + e32 + e33);

        const float c0 = v0;
        const float c1 = (e10 * v0 + e11 * v1) * r1;
        const float c2 = (e20 * v0 + e21 * v1 + e22 * v2) * r2;
        const float c3 = (e30 * v0 + e31 * v1 + e32 * v2 + e33 * v3) * r3;
#pragma unroll
        for (int e = 0; e < 4; ++e) {
            const float cv = (e == 0) ? c0 : (e == 1) ? c1 : (e == 2) ? c2 : c3;
            char* hp = Ct + (size_t)(2 * (off >> 5)) * ps
                     + (size_t)(t * 4 + e) * 64 + (off & 31) * 2;
            const bf16 hh = (bf16)cv;
            *(bf16*)hp = hh;
            *(bf16*)(hp + ps) = (bf16)(cv - (float)hh);
        }
    }
}

// ---------------------------------------------------------------------------
extern "C" void kernel_launch(void* const* d_in, const int* in_sizes, int n_in,
                              void* d_out, int out_size, void* d_ws, size_t ws_size,
                              hipStream_t stream)
{
    (void)in_sizes; (void)n_in; (void)out_size; (void)ws_size;
    const float* x[4]    = {(const float*)d_in[0], (const float*)d_in[3],
                            (const float*)d_in[6], (const float*)d_in[9]};
    const float* Win[4]  = {(const float*)d_in[1], (const float*)d_in[4],
                            (const float*)d_in[7], (const float*)d_in[10]};
    const float* Wout[4] = {(const float*)d_in[2], (const float*)d_in[5],
                            (const float*)d_in[8], (const float*)d_in[11]};
    const float* ln_g = (const float*)d_in[12];
    const float* ln_b = (const float*)d_in[13];
    const float* Wqkv = (const float*)d_in[14];
    const float* bqkv = (const float*)d_in[15];
    const float* Wo   = (const float*)d_in[16];
    const float* bo   = (const float*)d_in[17];
    float* out = (float*)d_out;

    const int dE[4]  = {128, 128, 1006, 104};
    const int KpE[4] = {128, 128, 1024, 128};
    const int NTOK = 16384, ROWS = 65536;
    const int TPC = 2048, RPC = TPC * 4, XR = 8192;   // fixed (178 MiB < proven ws)

    // tiled buffer bytes: 2*(Kp/32) planes * Rp * 64
    auto tbytes = [](int Rp, int Kp) { return (size_t)(Kp >> 4) * Rp * 64; };

    char* p = (char*)d_ws;
    auto alloc = [&](size_t bytes) -> char* {
        char* q = p; p += (bytes + 255) & ~(size_t)255; return q;
    };
    char* S = alloc(tbytes(ROWS, 512));               // 128 MiB
    char *WiT[4], *WoTt[4];
    for (int e = 0; e < 4; ++e) WiT[e]  = alloc(tbytes(512, KpE[e]));
    char* WgT = alloc(tbytes(1536, 512));
    char* WoT = alloc(tbytes(512, 512));
    for (int e = 0; e < 4; ++e) WoTt[e] = alloc(tbytes(KpE[e], 512));
    float* mu   = (float*)alloc((size_t)ROWS * 4);
    float* rstd = (float*)alloc((size_t)ROWS * 4);
    float* uV   = (float*)alloc(1536 * 4);
    float* cV   = (float*)alloc(1536 * 4);
    char* U = p;                                      // scratch: max ~40 MiB

    auto splitLaunch = [&](const float* in, int R, int K, int ldin,
                           char* ob, int Rp, int Kp, const float* cs) {
        const int total8 = (Rp * Kp) >> 3;
        int blocks = (total8 + 255) / 256; if (blocks > 4096) blocks = 4096;
        split_tiled<<<blocks, 256, 0, stream>>>(in, R, K, ldin, ob, Rp, Kp, cs);
    };

    // ---- weight prep ----
    for (int e = 0; e < 4; ++e)
        splitLaunch(Win[e], 512, dE[e], dE[e], WiT[e], 512, KpE[e], nullptr);
    splitLaunch(Wqkv, 1536, 512, 512, WgT, 1536, 512, ln_g);
    splitLaunch(Wo, 512, 512, 512, WoT, 512, 512, nullptr);
    for (int e = 0; e < 4; ++e)
        splitLaunch(Wout[e], dE[e], 512, 512, WoTt[e], KpE[e], 512, nullptr);
    qkv_uc<<<1536 / 4, 256, 0, stream>>>(Wqkv, ln_g, ln_b, bqkv, uV, cV);

    // ---- K1: x_e @ Win_e^T -> S (S-row = token*4 + e) ----
    for (int e = 0; e < 4; ++e) {
        const int rowsPer = (e == 2) ? XR : NTOK;
        for (int t0 = 0; t0 < NTOK; t0 += rowsPer) {
            splitLaunch(x[e] + (size_t)t0 * dE[e], rowsPer, dE[e], dE[e],
                        U, rowsPer, KpE[e], nullptr);
            const int nbx = rowsPer / 128;
            Op Ax{U, rowsPer, 0, 1};
            Op Bx{WiT[e], 512, 0, 1};
            gemm_ht<0><<<nbx * 4, 256, 0, stream>>>(
                Ax, Bx, nbx, KpE[e], 512,
                nullptr, 0, nullptr, S, ROWS, t0 * 4 + e, 4,
                nullptr, nullptr, nullptr, nullptr, nullptr, nullptr, 0);
        }
    }

    // ---- K2: LN stats ----
    ln_stats_t<<<ROWS / 4, 256, 0, stream>>>(S, ROWS, mu, rstd);

    // ---- chunks: QKV (fused LN) -> attn -> Wo (+residual into S) ----
    bf16* QKVc = (bf16*)U;                              // 24 MiB
    char* CTXt = U + (size_t)RPC * 1536 * 2;            // 16 MiB tiled
    for (int c = 0; c < NTOK / TPC; ++c) {
        const int rb = c * RPC;
        Op Aq{S, ROWS, rb, 1};
        Op Bq{WgT, 1536, 0, 1};
        gemm_ht<1><<<(RPC / 128) * 12, 256, 0, stream>>>(
            Aq, Bq, RPC / 128, 512, 1536,
            nullptr, 0, QKVc, nullptr, 0, 0, 0,
            mu + rb, rstd + rb, uV, cV, nullptr, nullptr, 0);
        attn_refine<<<TPC / 4, 256, 0, stream>>>(QKVc, CTXt, RPC, TPC);
        Op Ac{CTXt, RPC, 0, 1};
        Op Bo{WoT, 512, 0, 1};
        gemm_ht<2><<<(RPC / 128) * 4, 256, 0, stream>>>(
            Ac, Bo, RPC / 128, 512, 512,
            nullptr, 0, nullptr, S, ROWS, rb, 1,
            nullptr, nullptr, nullptr, nullptr, bo, nullptr, 0);
    }

    // ---- K5: out_e = S_e @ Wout_e^T + x_e ----
    size_t off = 0;
    for (int e = 0; e < 4; ++e) {
        Op As{S, ROWS, e, 4};
        Op Bw{WoTt[e], KpE[e], 0, 1};
        gemm_ht<3><<<(NTOK / 128) * (KpE[e] / 128), 256, 0, stream>>>(
            As, Bw, NTOK / 128, 512, dE[e],
            out + off, dE[e], nullptr, nullptr, 0, 0, 0,
            nullptr, nullptr, nullptr, nullptr, nullptr, x[e], dE[e]);
        off += (size_t)NTOK * dE[e];
    }
}